// Round 2
// baseline (116.098 us; speedup 1.0000x reference)
//
#include <hip/hip_runtime.h>
#include <hip/hip_bf16.h>

typedef __attribute__((ext_vector_type(8))) short short8;
typedef __attribute__((ext_vector_type(4))) float f32x4;

#define LN_EPS 1e-5f

__device__ __forceinline__ unsigned short bf16rn(float f) {
    unsigned int u = __builtin_bit_cast(unsigned int, f);
    u = u + 0x7fffu + ((u >> 16) & 1u);
    return (unsigned short)(u >> 16);
}

// ---------------- K0: W2 (128x2048 f32) -> bf16 ----------------
__global__ __launch_bounds__(256) void k_cvt_w2(const float* __restrict__ w2,
                                                unsigned short* __restrict__ o) {
    int i = (blockIdx.x * 256 + threadIdx.x) * 4;
    float4 v = *(const float4*)(w2 + i);
    ushort4 r;
    r.x = bf16rn(v.x); r.y = bf16rn(v.y); r.z = bf16rn(v.z); r.w = bf16rn(v.w);
    *(ushort4*)(o + i) = r;
}

// ---------------- K1: attn + LN1 -> x1 (=d_out), q ----------------
__global__ __launch_bounds__(256) void k_pre(const float* __restrict__ x,
                                             const float* __restrict__ theta,
                                             const float* __restrict__ phi,
                                             const float* __restrict__ gamma1,
                                             const float* __restrict__ beta1,
                                             float* __restrict__ x1,
                                             float* __restrict__ qv) {
    const int tid = threadIdx.x;
    const int g = tid >> 4, li = tid & 15;
    const int tok = blockIdx.x * 16 + g;

    const float* xr = x + (size_t)tok * 128 + li * 8;
    float4 va = *(const float4*)xr;
    float4 vb = *(const float4*)(xr + 4);
    float v[8] = {va.x, va.y, va.z, va.w, vb.x, vb.y, vb.z, vb.w};

    float c[8];
#pragma unroll
    for (int k = 0; k < 8; ++k) c[k] = __cosf(v[k] + theta[k]);
    float cp[8];
    cp[0] = c[0];
#pragma unroll
    for (int k = 1; k < 8; ++k) cp[k] = cp[k - 1] * c[k];

    float y[8];
    y[0] = v[0] + cp[7];
#pragma unroll
    for (int k = 1; k < 8; ++k) y[k] = v[k] + cp[k];

    float s1 = 0.f, s2 = 0.f;
#pragma unroll
    for (int k = 0; k < 8; ++k) { s1 += y[k]; s2 += y[k] * y[k]; }
#pragma unroll
    for (int m = 1; m < 16; m <<= 1) {
        s1 += __shfl_xor(s1, m);
        s2 += __shfl_xor(s2, m);
    }
    float mean = s1 * (1.f / 128.f);
    float var = s2 * (1.f / 128.f) - mean * mean;
    float rs = rsqrtf(var + LN_EPS);

    float4 ga = *(const float4*)(gamma1 + li * 8);
    float4 gb = *(const float4*)(gamma1 + li * 8 + 4);
    float4 ba = *(const float4*)(beta1 + li * 8);
    float4 bb = *(const float4*)(beta1 + li * 8 + 4);
    float gam[8] = {ga.x, ga.y, ga.z, ga.w, gb.x, gb.y, gb.z, gb.w};
    float bet[8] = {ba.x, ba.y, ba.z, ba.w, bb.x, bb.y, bb.z, bb.w};

    float o[8];
#pragma unroll
    for (int k = 0; k < 8; ++k) o[k] = (y[k] - mean) * rs * gam[k] + bet[k];

    float* x1r = x1 + (size_t)tok * 128 + li * 8;
    *(float4*)x1r = make_float4(o[0], o[1], o[2], o[3]);
    *(float4*)(x1r + 4) = make_float4(o[4], o[5], o[6], o[7]);

    if (li == 0) {
        float* qr = qv + (size_t)tok * 8;
#pragma unroll
        for (int k = 0; k < 8; ++k) qr[k] = __cosf(phi[k]) * __cosf(o[k]);
    }
}

// ---------------- K2: fused FFN with split-K across 4 waves ----------------
// Block = 4 waves, 32 tokens. Wave kc handles F-chunk [kc*512, kc*512+512).
// Partials tree-reduced via LDS (padded stride 36 -> conflict-free b128),
// wave 0 runs the fused bias+residual+LN2 epilogue.
__global__ __launch_bounds__(256, 4) void k_ffn(const float* __restrict__ x1,
                                                const float* __restrict__ qv,
                                                const unsigned short* __restrict__ w2b,
                                                const float* __restrict__ w1,
                                                const float* __restrict__ b1,
                                                const float* __restrict__ b2,
                                                const float* __restrict__ g2,
                                                const float* __restrict__ be2,
                                                float* __restrict__ out) {
    const int tid = threadIdx.x;
    const int kc = tid >> 6;      // wave index = K-chunk
    const int lane = tid & 63;
    const int li = lane & 15;     // tile row (A) / col (B,C)
    const int lg = lane >> 4;     // k-group
    const int Tb = blockIdx.x * 32;

    __shared__ float red[2][128][36];  // [region][col][token+pad]

    float q0[8], q1[8];
    {
        const float* qp = qv + (size_t)(Tb + li) * 8;
        float4 a = *(const float4*)qp, b = *(const float4*)(qp + 4);
        q0[0] = a.x; q0[1] = a.y; q0[2] = a.z; q0[3] = a.w;
        q0[4] = b.x; q0[5] = b.y; q0[6] = b.z; q0[7] = b.w;
        const float* qp1 = qv + (size_t)(Tb + 16 + li) * 8;
        float4 a1 = *(const float4*)qp1, b1x = *(const float4*)(qp1 + 4);
        q1[0] = a1.x; q1[1] = a1.y; q1[2] = a1.z; q1[3] = a1.w;
        q1[4] = b1x.x; q1[5] = b1x.y; q1[6] = b1x.z; q1[7] = b1x.w;
    }

    f32x4 acc0[8], acc1[8];
#pragma unroll
    for (int nt = 0; nt < 8; ++nt) {
        acc0[nt] = f32x4{0.f, 0.f, 0.f, 0.f};
        acc1[nt] = f32x4{0.f, 0.f, 0.f, 0.f};
    }

    for (int s = 0; s < 16; ++s) {
        const int fb = kc * 512 + s * 32 + lg * 8;

        short8 bfr[8];
#pragma unroll
        for (int nt = 0; nt < 8; ++nt)
            bfr[nt] = *(const short8*)(w2b + (size_t)(nt * 16 + li) * 2048 + fb);

        float4 b1a = *(const float4*)(b1 + fb);
        float4 b1b = *(const float4*)(b1 + fb + 4);
        float b1v[8] = {b1a.x, b1a.y, b1a.z, b1a.w, b1b.x, b1b.y, b1b.z, b1b.w};

        short8 a0, a1;
#pragma unroll
        for (int j = 0; j < 8; ++j) {
            const float* wr = w1 + (size_t)(fb + j) * 8;
            float4 wa = *(const float4*)wr;
            float4 wb = *(const float4*)(wr + 4);
            float d0 = b1v[j], d1 = b1v[j];
            d0 = fmaf(wa.x, q0[0], d0); d0 = fmaf(wa.y, q0[1], d0);
            d0 = fmaf(wa.z, q0[2], d0); d0 = fmaf(wa.w, q0[3], d0);
            d0 = fmaf(wb.x, q0[4], d0); d0 = fmaf(wb.y, q0[5], d0);
            d0 = fmaf(wb.z, q0[6], d0); d0 = fmaf(wb.w, q0[7], d0);
            d1 = fmaf(wa.x, q1[0], d1); d1 = fmaf(wa.y, q1[1], d1);
            d1 = fmaf(wa.z, q1[2], d1); d1 = fmaf(wa.w, q1[3], d1);
            d1 = fmaf(wb.x, q1[4], d1); d1 = fmaf(wb.y, q1[5], d1);
            d1 = fmaf(wb.z, q1[6], d1); d1 = fmaf(wb.w, q1[7], d1);
            d0 = fmaxf(d0, 0.f);
            d1 = fmaxf(d1, 0.f);
            a0[j] = (short)bf16rn(d0);
            a1[j] = (short)bf16rn(d1);
        }

#pragma unroll
        for (int nt = 0; nt < 8; ++nt) {
            acc0[nt] = __builtin_amdgcn_mfma_f32_16x16x32_bf16(a0, bfr[nt], acc0[nt], 0, 0, 0);
            acc1[nt] = __builtin_amdgcn_mfma_f32_16x16x32_bf16(a1, bfr[nt], acc1[nt], 0, 0, 0);
        }
    }

    // ---- tree reduction across the 4 K-chunk waves ----
    if (kc >= 2) {
        float (*R)[36] = red[kc - 2];
#pragma unroll
        for (int nt = 0; nt < 8; ++nt) {
            *(f32x4*)&R[nt * 16 + li][4 * lg] = acc0[nt];
            *(f32x4*)&R[nt * 16 + li][16 + 4 * lg] = acc1[nt];
        }
    }
    __syncthreads();
    if (kc < 2) {
        float (*R)[36] = red[kc];
#pragma unroll
        for (int nt = 0; nt < 8; ++nt) {
            acc0[nt] += *(const f32x4*)&R[nt * 16 + li][4 * lg];
            acc1[nt] += *(const f32x4*)&R[nt * 16 + li][16 + 4 * lg];
        }
    }
    if (kc == 1) {
        float (*R)[36] = red[1];
#pragma unroll
        for (int nt = 0; nt < 8; ++nt) {
            *(f32x4*)&R[nt * 16 + li][4 * lg] = acc0[nt];
            *(f32x4*)&R[nt * 16 + li][16 + 4 * lg] = acc1[nt];
        }
    }
    __syncthreads();
    if (kc == 0) {
        float (*R)[36] = red[1];
#pragma unroll
        for (int nt = 0; nt < 8; ++nt) {
            acc0[nt] += *(const f32x4*)&R[nt * 16 + li][4 * lg];
            acc1[nt] += *(const f32x4*)&R[nt * 16 + li][16 + 4 * lg];
        }

        float b2v[8], g2v[8], be2v[8];
#pragma unroll
        for (int nt = 0; nt < 8; ++nt) {
            int e = nt * 16 + li;
            b2v[nt] = b2[e]; g2v[nt] = g2[e]; be2v[nt] = be2[e];
        }

        auto epilogue = [&](const f32x4(&acc)[8], int mt) {
#pragma unroll
            for (int r = 0; r < 4; ++r) {
                const int trow = Tb + mt * 16 + lg * 4 + r;
                const float* x1r = x1 + (size_t)trow * 128;
                float vals[8];
                float s1 = 0.f, s2 = 0.f;
#pragma unroll
                for (int nt = 0; nt < 8; ++nt) {
                    float vv = acc[nt][r] + b2v[nt] + x1r[nt * 16 + li];
                    vals[nt] = vv;
                    s1 += vv;
                    s2 += vv * vv;
                }
#pragma unroll
                for (int m = 1; m < 16; m <<= 1) {
                    s1 += __shfl_xor(s1, m);
                    s2 += __shfl_xor(s2, m);
                }
                float mean = s1 * (1.f / 128.f);
                float var = s2 * (1.f / 128.f) - mean * mean;
                float rs = rsqrtf(var + LN_EPS);
                float* orow = out + (size_t)trow * 128;
#pragma unroll
                for (int nt = 0; nt < 8; ++nt)
                    orow[nt * 16 + li] = (vals[nt] - mean) * rs * g2v[nt] + be2v[nt];
            }
        };
        epilogue(acc0, 0);
        epilogue(acc1, 1);
    }
}

extern "C" void kernel_launch(void* const* d_in, const int* in_sizes, int n_in,
                              void* d_out, int out_size, void* d_ws, size_t ws_size,
                              hipStream_t stream) {
    const float* x      = (const float*)d_in[0];
    const float* theta  = (const float*)d_in[1];
    const float* phi    = (const float*)d_in[2];
    const float* w1     = (const float*)d_in[3];
    const float* b1     = (const float*)d_in[4];
    const float* w2     = (const float*)d_in[5];
    const float* b2     = (const float*)d_in[6];
    const float* gamma1 = (const float*)d_in[7];
    const float* beta1  = (const float*)d_in[8];
    const float* gamma2 = (const float*)d_in[9];
    const float* beta2  = (const float*)d_in[10];
    float* out = (float*)d_out;

    char* ws = (char*)d_ws;
    float* qv           = (float*)ws;                          // 1 MB
    unsigned short* w2b = (unsigned short*)(ws + (1 << 20));   // 512 KB

    k_cvt_w2<<<256, 256, 0, stream>>>(w2, w2b);
    k_pre<<<2048, 256, 0, stream>>>(x, theta, phi, gamma1, beta1, out, qv);
    k_ffn<<<1024, 256, 0, stream>>>(out, qv, w2b, w1, b1, b2, gamma2, beta2, out);
}

// Round 3
// 112.796 us; speedup vs baseline: 1.0293x; 1.0293x over previous
//
#include <hip/hip_runtime.h>
#include <hip/hip_bf16.h>

typedef __attribute__((ext_vector_type(8))) short short8;
typedef __attribute__((ext_vector_type(4))) float f32x4;

#define LN_EPS 1e-5f

__device__ __forceinline__ unsigned short bf16rn(float f) {
    unsigned int u = __builtin_bit_cast(unsigned int, f);
    u = u + 0x7fffu + ((u >> 16) & 1u);
    return (unsigned short)(u >> 16);
}

// ---------------- K0: W2 (128x2048 f32) -> bf16 ----------------
__global__ __launch_bounds__(256) void k_cvt_w2(const float* __restrict__ w2,
                                                unsigned short* __restrict__ o) {
    int i = (blockIdx.x * 256 + threadIdx.x) * 4;
    float4 v = *(const float4*)(w2 + i);
    ushort4 r;
    r.x = bf16rn(v.x); r.y = bf16rn(v.y); r.z = bf16rn(v.z); r.w = bf16rn(v.w);
    *(ushort4*)(o + i) = r;
}

// ---------------- K1: attn + LN1 -> x1 (=d_out), q ----------------
__global__ __launch_bounds__(256) void k_pre(const float* __restrict__ x,
                                             const float* __restrict__ theta,
                                             const float* __restrict__ phi,
                                             const float* __restrict__ gamma1,
                                             const float* __restrict__ beta1,
                                             float* __restrict__ x1,
                                             float* __restrict__ qv) {
    const int tid = threadIdx.x;
    const int g = tid >> 4, li = tid & 15;
    const int tok = blockIdx.x * 16 + g;

    const float* xr = x + (size_t)tok * 128 + li * 8;
    float4 va = *(const float4*)xr;
    float4 vb = *(const float4*)(xr + 4);
    float v[8] = {va.x, va.y, va.z, va.w, vb.x, vb.y, vb.z, vb.w};

    float c[8];
#pragma unroll
    for (int k = 0; k < 8; ++k) c[k] = __cosf(v[k] + theta[k]);
    float cp[8];
    cp[0] = c[0];
#pragma unroll
    for (int k = 1; k < 8; ++k) cp[k] = cp[k - 1] * c[k];

    float y[8];
    y[0] = v[0] + cp[7];
#pragma unroll
    for (int k = 1; k < 8; ++k) y[k] = v[k] + cp[k];

    float s1 = 0.f, s2 = 0.f;
#pragma unroll
    for (int k = 0; k < 8; ++k) { s1 += y[k]; s2 += y[k] * y[k]; }
#pragma unroll
    for (int m = 1; m < 16; m <<= 1) {
        s1 += __shfl_xor(s1, m);
        s2 += __shfl_xor(s2, m);
    }
    float mean = s1 * (1.f / 128.f);
    float var = s2 * (1.f / 128.f) - mean * mean;
    float rs = rsqrtf(var + LN_EPS);

    float4 ga = *(const float4*)(gamma1 + li * 8);
    float4 gb = *(const float4*)(gamma1 + li * 8 + 4);
    float4 ba = *(const float4*)(beta1 + li * 8);
    float4 bb = *(const float4*)(beta1 + li * 8 + 4);
    float gam[8] = {ga.x, ga.y, ga.z, ga.w, gb.x, gb.y, gb.z, gb.w};
    float bet[8] = {ba.x, ba.y, ba.z, ba.w, bb.x, bb.y, bb.z, bb.w};

    float o[8];
#pragma unroll
    for (int k = 0; k < 8; ++k) o[k] = (y[k] - mean) * rs * gam[k] + bet[k];

    float* x1r = x1 + (size_t)tok * 128 + li * 8;
    *(float4*)x1r = make_float4(o[0], o[1], o[2], o[3]);
    *(float4*)(x1r + 4) = make_float4(o[4], o[5], o[6], o[7]);

    if (li == 0) {
        float* qr = qv + (size_t)tok * 8;
#pragma unroll
        for (int k = 0; k < 8; ++k) qr[k] = __cosf(phi[k]) * __cosf(o[k]);
    }
}

// ---------------- K2: fused FFN, LDS-staged W2, M-split waves ----------------
// Block = 4 waves x 16 tokens = 64 tokens. All waves share the K-step.
// W2 chunk (64 feats x 128 cols bf16 = 16 KB) double-buffered in LDS via
// global_load_lds(16B); XOR chunk-swizzle applied on the GLOBAL source
// (linear LDS dest) and re-applied on the ds_read -> conflict-free.
__global__ __launch_bounds__(256) void k_ffn(const float* __restrict__ x1,
                                             const float* __restrict__ qv,
                                             const unsigned short* __restrict__ w2b,
                                             const float* __restrict__ w1,
                                             const float* __restrict__ b1,
                                             const float* __restrict__ b2,
                                             const float* __restrict__ g2,
                                             const float* __restrict__ be2,
                                             float* __restrict__ out) {
    const int tid = threadIdx.x;
    const int wv = tid >> 6;
    const int lane = tid & 63;
    const int li = lane & 15;   // A row (token) / B,C col
    const int lg = lane >> 4;   // k-group
    const int Tb = blockIdx.x * 64;
    const int tok = Tb + wv * 16 + li;

    __shared__ __align__(16) unsigned short Bs[2][128 * 64];  // [buf][row*64 + k]

    float q0[8];
    {
        const float* qp = qv + (size_t)tok * 8;
        float4 a = *(const float4*)qp, b = *(const float4*)(qp + 4);
        q0[0] = a.x; q0[1] = a.y; q0[2] = a.z; q0[3] = a.w;
        q0[4] = b.x; q0[5] = b.y; q0[6] = b.z; q0[7] = b.w;
    }

    f32x4 acc[8];
#pragma unroll
    for (int nt = 0; nt < 8; ++nt) acc[nt] = f32x4{0.f, 0.f, 0.f, 0.f};

    // staging lane constants: lane covers (row = slab+lane/8, chunk = lane%8)
    const int srow = lane >> 3;
    const int scs = (lane & 7) ^ srow;  // pre-swizzled source chunk

    auto stage = [&](int buf, int kb) {
#pragma unroll
        for (int r = 0; r < 4; ++r) {
            const int e0 = r * 32 + wv * 8;  // wave-uniform row base
            const unsigned short* src =
                w2b + (size_t)(e0 + srow) * 2048 + kb + scs * 8;
            unsigned short* dst = &Bs[buf][e0 * 64];
            __builtin_amdgcn_global_load_lds(
                (const __attribute__((address_space(1))) unsigned int*)src,
                (__attribute__((address_space(3))) unsigned int*)dst,
                16, 0, 0);
        }
    };

    stage(0, 0);
    __syncthreads();

    for (int kbi = 0; kbi < 32; ++kbi) {
        const int buf = kbi & 1;
        if (kbi < 31) stage(buf ^ 1, (kbi + 1) * 64);

#pragma unroll
        for (int kk = 0; kk < 2; ++kk) {
            const int fb = kbi * 64 + kk * 32 + lg * 8;

            // B fragments from LDS (swizzled chunk) -> ds_read_b128, 2-way free
            short8 bfr[8];
#pragma unroll
            for (int nt = 0; nt < 8; ++nt) {
                const int row = nt * 16 + li;
                const int cs = (kk * 4 + lg) ^ (li & 7);
                bfr[nt] = *(const short8*)&Bs[buf][row * 64 + cs * 8];
            }

            float4 b1a = *(const float4*)(b1 + fb);
            float4 b1b = *(const float4*)(b1 + fb + 4);
            float b1v[8] = {b1a.x, b1a.y, b1a.z, b1a.w, b1b.x, b1b.y, b1b.z, b1b.w};

            // A fragment: h = relu(W1 q + b1), fp32 exact
            short8 a0;
#pragma unroll
            for (int j = 0; j < 8; ++j) {
                const float* wr = w1 + (size_t)(fb + j) * 8;
                float4 wa = *(const float4*)wr;
                float4 wb = *(const float4*)(wr + 4);
                float d0 = b1v[j];
                d0 = fmaf(wa.x, q0[0], d0); d0 = fmaf(wa.y, q0[1], d0);
                d0 = fmaf(wa.z, q0[2], d0); d0 = fmaf(wa.w, q0[3], d0);
                d0 = fmaf(wb.x, q0[4], d0); d0 = fmaf(wb.y, q0[5], d0);
                d0 = fmaf(wb.z, q0[6], d0); d0 = fmaf(wb.w, q0[7], d0);
                d0 = fmaxf(d0, 0.f);
                a0[j] = (short)bf16rn(d0);
            }

#pragma unroll
            for (int nt = 0; nt < 8; ++nt)
                acc[nt] = __builtin_amdgcn_mfma_f32_16x16x32_bf16(a0, bfr[nt], acc[nt], 0, 0, 0);
        }
        __syncthreads();  // stage(buf^1) done + all waves done reading buf
    }

    // ---- epilogue: +b2, +x1 residual, LN2 (wave-local) ----
    float b2v[8], g2v[8], be2v[8];
#pragma unroll
    for (int nt = 0; nt < 8; ++nt) {
        int e = nt * 16 + li;
        b2v[nt] = b2[e]; g2v[nt] = g2[e]; be2v[nt] = be2[e];
    }

#pragma unroll
    for (int r = 0; r < 4; ++r) {
        const int trow = Tb + wv * 16 + lg * 4 + r;
        const float* x1r = x1 + (size_t)trow * 128;
        float vals[8];
        float s1 = 0.f, s2 = 0.f;
#pragma unroll
        for (int nt = 0; nt < 8; ++nt) {
            float vv = acc[nt][r] + b2v[nt] + x1r[nt * 16 + li];
            vals[nt] = vv;
            s1 += vv;
            s2 += vv * vv;
        }
#pragma unroll
        for (int m = 1; m < 16; m <<= 1) {
            s1 += __shfl_xor(s1, m);
            s2 += __shfl_xor(s2, m);
        }
        float mean = s1 * (1.f / 128.f);
        float var = s2 * (1.f / 128.f) - mean * mean;
        float rs = rsqrtf(var + LN_EPS);
        float* orow = out + (size_t)trow * 128;
#pragma unroll
        for (int nt = 0; nt < 8; ++nt)
            orow[nt * 16 + li] = (vals[nt] - mean) * rs * g2v[nt] + be2v[nt];
    }
}

extern "C" void kernel_launch(void* const* d_in, const int* in_sizes, int n_in,
                              void* d_out, int out_size, void* d_ws, size_t ws_size,
                              hipStream_t stream) {
    const float* x      = (const float*)d_in[0];
    const float* theta  = (const float*)d_in[1];
    const float* phi    = (const float*)d_in[2];
    const float* w1     = (const float*)d_in[3];
    const float* b1     = (const float*)d_in[4];
    const float* w2     = (const float*)d_in[5];
    const float* b2     = (const float*)d_in[6];
    const float* gamma1 = (const float*)d_in[7];
    const float* beta1  = (const float*)d_in[8];
    const float* gamma2 = (const float*)d_in[9];
    const float* beta2  = (const float*)d_in[10];
    float* out = (float*)d_out;

    char* ws = (char*)d_ws;
    float* qv           = (float*)ws;                          // 1 MB
    unsigned short* w2b = (unsigned short*)(ws + (1 << 20));   // 512 KB

    k_cvt_w2<<<256, 256, 0, stream>>>(w2, w2b);
    k_pre<<<2048, 256, 0, stream>>>(x, theta, phi, gamma1, beta1, out, qv);
    k_ffn<<<512, 256, 0, stream>>>(out, qv, w2b, w1, b1, b2, gamma2, beta2, out);
}

// Round 4
// 62.830 us; speedup vs baseline: 1.8478x; 1.7953x over previous
//
#include <hip/hip_runtime.h>
#include <hip/hip_bf16.h>

typedef __attribute__((ext_vector_type(8))) short short8;
typedef __attribute__((ext_vector_type(4))) float f32x4;
typedef __attribute__((ext_vector_type(4))) int int4v;

#define LN_EPS 1e-5f

__device__ __forceinline__ unsigned short bf16rn(float f) {
    unsigned int u = __builtin_bit_cast(unsigned int, f);
    u = u + 0x7fffu + ((u >> 16) & 1u);
    return (unsigned short)(u >> 16);
}

__device__ __forceinline__ unsigned cvt_pk(float lo, float hi) {
    unsigned r;
    asm("v_cvt_pk_bf16_f32 %0, %1, %2" : "=v"(r) : "v"(lo), "v"(hi));
    return r;
}

// ---------------- K0: prep W2->bf16 and W1pad (2048x32 bf16, col8=b1) ----------------
__global__ __launch_bounds__(256) void k_prep(const float* __restrict__ w2,
                                              const float* __restrict__ w1,
                                              const float* __restrict__ b1,
                                              unsigned short* __restrict__ w2b,
                                              unsigned short* __restrict__ w1p) {
    const int bid = blockIdx.x;
    if (bid < 256) {
        int i = (bid * 256 + threadIdx.x) * 4;
        float4 v = *(const float4*)(w2 + i);
        ushort4 r;
        r.x = bf16rn(v.x); r.y = bf16rn(v.y); r.z = bf16rn(v.z); r.w = bf16rn(v.w);
        *(ushort4*)(w2b + i) = r;
    } else {
        int f = (bid - 256) * 256 + threadIdx.x;  // 0..2047
        float4 wa = *(const float4*)(w1 + (size_t)f * 8);
        float4 wb = *(const float4*)(w1 + (size_t)f * 8 + 4);
        short8 r0, r1;
        r0[0] = (short)bf16rn(wa.x); r0[1] = (short)bf16rn(wa.y);
        r0[2] = (short)bf16rn(wa.z); r0[3] = (short)bf16rn(wa.w);
        r0[4] = (short)bf16rn(wb.x); r0[5] = (short)bf16rn(wb.y);
        r0[6] = (short)bf16rn(wb.z); r0[7] = (short)bf16rn(wb.w);
        r1 = short8{0, 0, 0, 0, 0, 0, 0, 0};
        r1[0] = (short)bf16rn(b1[f]);  // multiplied by qpad[8]=1.0
        short8 z = short8{0, 0, 0, 0, 0, 0, 0, 0};
        unsigned short* row = w1p + (size_t)f * 32;
        *(short8*)(row) = r0;
        *(short8*)(row + 8) = r1;
        *(short8*)(row + 16) = z;
        *(short8*)(row + 24) = z;
    }
}

// ---------------- K1: attn + LN1 -> x1 (=d_out), qpad (bf16, K=32 padded) ----------------
__global__ __launch_bounds__(256) void k_pre(const float* __restrict__ x,
                                             const float* __restrict__ theta,
                                             const float* __restrict__ phi,
                                             const float* __restrict__ gamma1,
                                             const float* __restrict__ beta1,
                                             float* __restrict__ x1,
                                             unsigned short* __restrict__ qpad) {
    const int tid = threadIdx.x;
    const int g = tid >> 4, li = tid & 15;
    const int tok = blockIdx.x * 16 + g;

    const float* xr = x + (size_t)tok * 128 + li * 8;
    float4 va = *(const float4*)xr;
    float4 vb = *(const float4*)(xr + 4);
    float v[8] = {va.x, va.y, va.z, va.w, vb.x, vb.y, vb.z, vb.w};

    float c[8];
#pragma unroll
    for (int k = 0; k < 8; ++k) c[k] = __cosf(v[k] + theta[k]);
    float cp[8];
    cp[0] = c[0];
#pragma unroll
    for (int k = 1; k < 8; ++k) cp[k] = cp[k - 1] * c[k];

    float y[8];
    y[0] = v[0] + cp[7];
#pragma unroll
    for (int k = 1; k < 8; ++k) y[k] = v[k] + cp[k];

    float s1 = 0.f, s2 = 0.f;
#pragma unroll
    for (int k = 0; k < 8; ++k) { s1 += y[k]; s2 += y[k] * y[k]; }
#pragma unroll
    for (int m = 1; m < 16; m <<= 1) {
        s1 += __shfl_xor(s1, m);
        s2 += __shfl_xor(s2, m);
    }
    float mean = s1 * (1.f / 128.f);
    float var = s2 * (1.f / 128.f) - mean * mean;
    float rs = rsqrtf(var + LN_EPS);

    float4 ga = *(const float4*)(gamma1 + li * 8);
    float4 gb = *(const float4*)(gamma1 + li * 8 + 4);
    float4 ba = *(const float4*)(beta1 + li * 8);
    float4 bb = *(const float4*)(beta1 + li * 8 + 4);
    float gam[8] = {ga.x, ga.y, ga.z, ga.w, gb.x, gb.y, gb.z, gb.w};
    float bet[8] = {ba.x, ba.y, ba.z, ba.w, bb.x, bb.y, bb.z, bb.w};

    float o[8];
#pragma unroll
    for (int k = 0; k < 8; ++k) o[k] = (y[k] - mean) * rs * gam[k] + bet[k];

    float* x1r = x1 + (size_t)tok * 128 + li * 8;
    *(float4*)x1r = make_float4(o[0], o[1], o[2], o[3]);
    *(float4*)(x1r + 4) = make_float4(o[4], o[5], o[6], o[7]);

    // qpad row: [q0..q7, 1.0, 0...0] in bf16 (32 elems)
    if (li == 0) {
        short8 qr;
#pragma unroll
        for (int k = 0; k < 8; ++k)
            qr[k] = (short)bf16rn(__cosf(phi[k]) * __cosf(o[k]));
        *(short8*)(qpad + (size_t)tok * 32) = qr;
    } else if (li < 4) {
        short8 z = short8{0, 0, 0, 0, 0, 0, 0, 0};
        if (li == 1) z[0] = (short)0x3F80;  // 1.0bf16 -> picks up b1 column
        *(short8*)(qpad + (size_t)tok * 32 + li * 8) = z;
    }
}

// ---------------- K2: fused FFN, both GEMMs on MFMA ----------------
// Block = 4 waves x 32 tokens = 128 tokens; grid 256. W2 chunk (128x64 bf16)
// double-buffered in LDS (XOR chunk-swizzle, pre-swizzled global source).
// GEMM1 (h = relu(q*W1^T + b1)) via 2 MFMAs with PERMUTED A-rows
// arow(m,li)=8*(li>>2)+4m+(li&3) so its C/D output lands exactly in GEMM2's
// A-fragment layout (lane holds feats 8*lg..8*lg+7 of its token): no shuffles.
__global__ __launch_bounds__(256) void k_ffn(const float* __restrict__ x1,
                                             const unsigned short* __restrict__ qpad,
                                             const unsigned short* __restrict__ w2b,
                                             const unsigned short* __restrict__ w1p,
                                             const float* __restrict__ b2,
                                             const float* __restrict__ g2,
                                             const float* __restrict__ be2,
                                             float* __restrict__ out) {
    const int tid = threadIdx.x;
    const int wv = tid >> 6;
    const int lane = tid & 63;
    const int li = lane & 15;
    const int lg = lane >> 4;
    const int Tb = blockIdx.x * 128;
    const int t0 = Tb + wv * 32;  // wave token base (2 M-tiles)

    __shared__ __align__(16) unsigned short Bs[2][128 * 64];

    // q fragments (k-invariant): B[k=8lg+j][col=li] = qpad[tok][8lg+j]
    short8 qf0 = *(const short8*)(qpad + (size_t)(t0 + li) * 32 + lg * 8);
    short8 qf1 = *(const short8*)(qpad + (size_t)(t0 + 16 + li) * 32 + lg * 8);

    // A-row offset (elements) for m=0; m=1 adds 4*32=128
    const int arow0 = (8 * (li >> 2) + (li & 3)) * 32 + lg * 8;

    f32x4 acc0[8], acc1[8];
#pragma unroll
    for (int nt = 0; nt < 8; ++nt) {
        acc0[nt] = f32x4{0.f, 0.f, 0.f, 0.f};
        acc1[nt] = f32x4{0.f, 0.f, 0.f, 0.f};
    }

    const int srow = lane >> 3;
    const int scs = (lane & 7) ^ srow;  // pre-swizzled source chunk

    auto stage = [&](int buf, int kb) {
#pragma unroll
        for (int r = 0; r < 4; ++r) {
            const int e0 = r * 32 + wv * 8;
            const unsigned short* src =
                w2b + (size_t)(e0 + srow) * 2048 + kb + scs * 8;
            unsigned short* dst = &Bs[buf][e0 * 64];
            __builtin_amdgcn_global_load_lds(
                (const __attribute__((address_space(1))) unsigned int*)src,
                (__attribute__((address_space(3))) unsigned int*)dst,
                16, 0, 0);
        }
    };

    stage(0, 0);
    __syncthreads();

    const f32x4 zero4 = f32x4{0.f, 0.f, 0.f, 0.f};

    for (int kbi = 0; kbi < 32; ++kbi) {
        const int buf = kbi & 1;
        if (kbi < 31) stage(buf ^ 1, (kbi + 1) * 64);

#pragma unroll
        for (int kk = 0; kk < 2; ++kk) {
            const int fb = kbi * 64 + kk * 32;

            // GEMM1 A-frags (W1pad, permuted rows)
            const unsigned short* wbase = w1p + (size_t)fb * 32;
            short8 A0 = *(const short8*)(wbase + arow0);
            short8 A1 = *(const short8*)(wbase + arow0 + 128);

            // GEMM2 B-frags from LDS (swizzled chunks; conflict-free)
            short8 bfr[8];
#pragma unroll
            for (int nt = 0; nt < 8; ++nt) {
                const int row = nt * 16 + li;
                const int cs = (kk * 4 + lg) ^ (li & 7);
                bfr[nt] = *(const short8*)&Bs[buf][row * 64 + cs * 8];
            }

            // ---- tile 0 ----
            {
                f32x4 p0 = __builtin_amdgcn_mfma_f32_16x16x32_bf16(A0, qf0, zero4, 0, 0, 0);
                f32x4 p1 = __builtin_amdgcn_mfma_f32_16x16x32_bf16(A1, qf0, zero4, 0, 0, 0);
#pragma unroll
                for (int r = 0; r < 4; ++r) {
                    p0[r] = fmaxf(p0[r], 0.f);
                    p1[r] = fmaxf(p1[r], 0.f);
                }
                int4v ai = {(int)cvt_pk(p0[0], p0[1]), (int)cvt_pk(p0[2], p0[3]),
                            (int)cvt_pk(p1[0], p1[1]), (int)cvt_pk(p1[2], p1[3])};
                short8 a2 = __builtin_bit_cast(short8, ai);
#pragma unroll
                for (int nt = 0; nt < 8; ++nt)
                    acc0[nt] = __builtin_amdgcn_mfma_f32_16x16x32_bf16(a2, bfr[nt], acc0[nt], 0, 0, 0);
            }
            // ---- tile 1 ----
            {
                f32x4 p0 = __builtin_amdgcn_mfma_f32_16x16x32_bf16(A0, qf1, zero4, 0, 0, 0);
                f32x4 p1 = __builtin_amdgcn_mfma_f32_16x16x32_bf16(A1, qf1, zero4, 0, 0, 0);
#pragma unroll
                for (int r = 0; r < 4; ++r) {
                    p0[r] = fmaxf(p0[r], 0.f);
                    p1[r] = fmaxf(p1[r], 0.f);
                }
                int4v ai = {(int)cvt_pk(p0[0], p0[1]), (int)cvt_pk(p0[2], p0[3]),
                            (int)cvt_pk(p1[0], p1[1]), (int)cvt_pk(p1[2], p1[3])};
                short8 a2 = __builtin_bit_cast(short8, ai);
#pragma unroll
                for (int nt = 0; nt < 8; ++nt)
                    acc1[nt] = __builtin_amdgcn_mfma_f32_16x16x32_bf16(a2, bfr[nt], acc1[nt], 0, 0, 0);
            }
        }
        __syncthreads();
    }

    // ---- epilogue: +b2, +x1 residual, LN2 ----
    float b2v[8], g2v[8], be2v[8];
#pragma unroll
    for (int nt = 0; nt < 8; ++nt) {
        int e = nt * 16 + li;
        b2v[nt] = b2[e]; g2v[nt] = g2[e]; be2v[nt] = be2[e];
    }

    auto epilogue = [&](const f32x4(&acc)[8], int mt) {
#pragma unroll
        for (int r = 0; r < 4; ++r) {
            const int trow = t0 + mt * 16 + lg * 4 + r;
            const float* x1r = x1 + (size_t)trow * 128;
            float vals[8];
            float s1 = 0.f, s2 = 0.f;
#pragma unroll
            for (int nt = 0; nt < 8; ++nt) {
                float vv = acc[nt][r] + b2v[nt] + x1r[nt * 16 + li];
                vals[nt] = vv;
                s1 += vv;
                s2 += vv * vv;
            }
#pragma unroll
            for (int m = 1; m < 16; m <<= 1) {
                s1 += __shfl_xor(s1, m);
                s2 += __shfl_xor(s2, m);
            }
            float mean = s1 * (1.f / 128.f);
            float var = s2 * (1.f / 128.f) - mean * mean;
            float rs = rsqrtf(var + LN_EPS);
            float* orow = out + (size_t)trow * 128;
#pragma unroll
            for (int nt = 0; nt < 8; ++nt)
                orow[nt * 16 + li] = (vals[nt] - mean) * rs * g2v[nt] + be2v[nt];
        }
    };
    epilogue(acc0, 0);
    epilogue(acc1, 1);
}

extern "C" void kernel_launch(void* const* d_in, const int* in_sizes, int n_in,
                              void* d_out, int out_size, void* d_ws, size_t ws_size,
                              hipStream_t stream) {
    const float* x      = (const float*)d_in[0];
    const float* theta  = (const float*)d_in[1];
    const float* phi    = (const float*)d_in[2];
    const float* w1     = (const float*)d_in[3];
    const float* b1     = (const float*)d_in[4];
    const float* w2     = (const float*)d_in[5];
    const float* b2     = (const float*)d_in[6];
    const float* gamma1 = (const float*)d_in[7];
    const float* beta1  = (const float*)d_in[8];
    const float* gamma2 = (const float*)d_in[9];
    const float* beta2  = (const float*)d_in[10];
    float* out = (float*)d_out;

    char* ws = (char*)d_ws;
    unsigned short* w2b  = (unsigned short*)ws;                  // 512 KB
    unsigned short* w1p  = (unsigned short*)(ws + (512 << 10));  // 128 KB
    unsigned short* qpad = (unsigned short*)(ws + (1 << 20));    // 2 MB

    k_prep<<<264, 256, 0, stream>>>(w2, w1, b1, w2b, w1p);
    k_pre<<<2048, 256, 0, stream>>>(x, theta, phi, gamma1, beta1, out, qpad);
    k_ffn<<<256, 256, 0, stream>>>(out, qpad, w2b, w1p, b2, gamma2, beta2, out);
}

// Round 5
// 48.643 us; speedup vs baseline: 2.3867x; 1.2917x over previous
//
#include <hip/hip_runtime.h>
#include <hip/hip_bf16.h>

typedef __attribute__((ext_vector_type(8))) short short8;
typedef __attribute__((ext_vector_type(4))) float f32x4;
typedef __attribute__((ext_vector_type(4))) int int4v;

#define LN_EPS 1e-5f

__device__ __forceinline__ unsigned short bf16rn(float f) {
    unsigned int u = __builtin_bit_cast(unsigned int, f);
    u = u + 0x7fffu + ((u >> 16) & 1u);
    return (unsigned short)(u >> 16);
}

__device__ __forceinline__ unsigned cvt_pk(float lo, float hi) {
    unsigned r;
    asm("v_cvt_pk_bf16_f32 %0, %1, %2" : "=v"(r) : "v"(lo), "v"(hi));
    return r;
}

// ---------------- K0: prep W2->bf16 and W1pad (2048x32 bf16, col8=b1) ----------------
__global__ __launch_bounds__(256) void k_prep(const float* __restrict__ w2,
                                              const float* __restrict__ w1,
                                              const float* __restrict__ b1,
                                              unsigned short* __restrict__ w2b,
                                              unsigned short* __restrict__ w1p) {
    const int bid = blockIdx.x;
    if (bid < 256) {
        int i = (bid * 256 + threadIdx.x) * 4;
        float4 v = *(const float4*)(w2 + i);
        ushort4 r;
        r.x = bf16rn(v.x); r.y = bf16rn(v.y); r.z = bf16rn(v.z); r.w = bf16rn(v.w);
        *(ushort4*)(w2b + i) = r;
    } else {
        int f = (bid - 256) * 256 + threadIdx.x;  // 0..2047
        float4 wa = *(const float4*)(w1 + (size_t)f * 8);
        float4 wb = *(const float4*)(w1 + (size_t)f * 8 + 4);
        short8 r0, r1;
        r0[0] = (short)bf16rn(wa.x); r0[1] = (short)bf16rn(wa.y);
        r0[2] = (short)bf16rn(wa.z); r0[3] = (short)bf16rn(wa.w);
        r0[4] = (short)bf16rn(wb.x); r0[5] = (short)bf16rn(wb.y);
        r0[6] = (short)bf16rn(wb.z); r0[7] = (short)bf16rn(wb.w);
        r1 = short8{0, 0, 0, 0, 0, 0, 0, 0};
        r1[0] = (short)bf16rn(b1[f]);  // multiplied by qpad[8]=1.0
        short8 z = short8{0, 0, 0, 0, 0, 0, 0, 0};
        unsigned short* row = w1p + (size_t)f * 32;
        *(short8*)(row) = r0;
        *(short8*)(row + 8) = r1;
        *(short8*)(row + 16) = z;
        *(short8*)(row + 24) = z;
    }
}

// ---------------- K1: attn + LN1 -> x1 (=d_out), qpad (bf16, K=32 padded) ----------------
__global__ __launch_bounds__(256) void k_pre(const float* __restrict__ x,
                                             const float* __restrict__ theta,
                                             const float* __restrict__ phi,
                                             const float* __restrict__ gamma1,
                                             const float* __restrict__ beta1,
                                             float* __restrict__ x1,
                                             unsigned short* __restrict__ qpad) {
    const int tid = threadIdx.x;
    const int g = tid >> 4, li = tid & 15;
    const int tok = blockIdx.x * 16 + g;

    const float* xr = x + (size_t)tok * 128 + li * 8;
    float4 va = *(const float4*)xr;
    float4 vb = *(const float4*)(xr + 4);
    float v[8] = {va.x, va.y, va.z, va.w, vb.x, vb.y, vb.z, vb.w};

    float c[8];
#pragma unroll
    for (int k = 0; k < 8; ++k) c[k] = __cosf(v[k] + theta[k]);
    float cp[8];
    cp[0] = c[0];
#pragma unroll
    for (int k = 1; k < 8; ++k) cp[k] = cp[k - 1] * c[k];

    float y[8];
    y[0] = v[0] + cp[7];
#pragma unroll
    for (int k = 1; k < 8; ++k) y[k] = v[k] + cp[k];

    float s1 = 0.f, s2 = 0.f;
#pragma unroll
    for (int k = 0; k < 8; ++k) { s1 += y[k]; s2 += y[k] * y[k]; }
#pragma unroll
    for (int m = 1; m < 16; m <<= 1) {
        s1 += __shfl_xor(s1, m);
        s2 += __shfl_xor(s2, m);
    }
    float mean = s1 * (1.f / 128.f);
    float var = s2 * (1.f / 128.f) - mean * mean;
    float rs = rsqrtf(var + LN_EPS);

    float4 ga = *(const float4*)(gamma1 + li * 8);
    float4 gb = *(const float4*)(gamma1 + li * 8 + 4);
    float4 ba = *(const float4*)(beta1 + li * 8);
    float4 bb = *(const float4*)(beta1 + li * 8 + 4);
    float gam[8] = {ga.x, ga.y, ga.z, ga.w, gb.x, gb.y, gb.z, gb.w};
    float bet[8] = {ba.x, ba.y, ba.z, ba.w, bb.x, bb.y, bb.z, bb.w};

    float o[8];
#pragma unroll
    for (int k = 0; k < 8; ++k) o[k] = (y[k] - mean) * rs * gam[k] + bet[k];

    float* x1r = x1 + (size_t)tok * 128 + li * 8;
    *(float4*)x1r = make_float4(o[0], o[1], o[2], o[3]);
    *(float4*)(x1r + 4) = make_float4(o[4], o[5], o[6], o[7]);

    // qpad row: [q0..q7, 1.0, 0...0] in bf16 (32 elems)
    if (li == 0) {
        short8 qr;
#pragma unroll
        for (int k = 0; k < 8; ++k)
            qr[k] = (short)bf16rn(__cosf(phi[k]) * __cosf(o[k]));
        *(short8*)(qpad + (size_t)tok * 32) = qr;
    } else if (li < 4) {
        short8 z = short8{0, 0, 0, 0, 0, 0, 0, 0};
        if (li == 1) z[0] = (short)0x3F80;  // 1.0bf16 -> picks up b1 column
        *(short8*)(qpad + (size_t)tok * 32 + li * 8) = z;
    }
}

// ---------------- K2: fused FFN, both GEMMs on MFMA, split-K across wave halves ----------------
// Block = 8 waves (512 thr), 128 tokens, grid 256 (1 block/CU, 2 waves/SIMD).
// Waves 0-3: F[0:1024), waves 4-7: F[1024:2048); each wave 2 M-tiles (32 tok).
// W2 K-chunks (128x64 bf16) double-buffered in LDS per half (XOR chunk-swizzle,
// pre-swizzled global source). GEMM1 h=relu(q*W1^T+b1) on MFMA with permuted
// A-rows so its output IS GEMM2's A-fragment. Upper half dumps partial acc to
// padded LDS; lower half reduces + fused bias/residual/LN2 epilogue.
__global__ __launch_bounds__(512) void k_ffn(const float* __restrict__ x1,
                                             const unsigned short* __restrict__ qpad,
                                             const unsigned short* __restrict__ w2b,
                                             const unsigned short* __restrict__ w1p,
                                             const float* __restrict__ b2,
                                             const float* __restrict__ g2,
                                             const float* __restrict__ be2,
                                             float* __restrict__ out) {
    const int tid = threadIdx.x;
    const int wv = tid >> 6;     // 0..7
    const int hf = wv >> 2;      // K-half
    const int wvh = wv & 3;      // wave within half
    const int lane = tid & 63;
    const int li = lane & 15;
    const int lg = lane >> 4;
    const int Tb = blockIdx.x * 128;
    const int t0 = Tb + wvh * 32;  // wave token base (2 M-tiles)

    __shared__ __align__(16) unsigned short Bs[2][2][128 * 64];  // [half][buf]
    __shared__ float red[128][132];                              // padded: 2-way free

    // q fragments (k-invariant, shared by both halves)
    short8 qf0 = *(const short8*)(qpad + (size_t)(t0 + li) * 32 + lg * 8);
    short8 qf1 = *(const short8*)(qpad + (size_t)(t0 + 16 + li) * 32 + lg * 8);

    // GEMM1 A-row offset (elements) for m=0; m=1 adds 4*32=128
    const int arow0 = (8 * (li >> 2) + (li & 3)) * 32 + lg * 8;

    f32x4 acc0[8], acc1[8];
#pragma unroll
    for (int nt = 0; nt < 8; ++nt) {
        acc0[nt] = f32x4{0.f, 0.f, 0.f, 0.f};
        acc1[nt] = f32x4{0.f, 0.f, 0.f, 0.f};
    }

    const int srow = lane >> 3;
    const int scs = (lane & 7) ^ srow;  // pre-swizzled source chunk

    auto stage = [&](int buf, int kb_local) {
        const int kb = hf * 1024 + kb_local;
#pragma unroll
        for (int r = 0; r < 4; ++r) {
            const int e0 = r * 32 + wvh * 8;  // wave-uniform row base
            const unsigned short* src =
                w2b + (size_t)(e0 + srow) * 2048 + kb + scs * 8;
            unsigned short* dst = &Bs[hf][buf][e0 * 64];
            __builtin_amdgcn_global_load_lds(
                (const __attribute__((address_space(1))) unsigned int*)src,
                (__attribute__((address_space(3))) unsigned int*)dst,
                16, 0, 0);
        }
    };

    stage(0, 0);
    __syncthreads();

    const f32x4 zero4 = f32x4{0.f, 0.f, 0.f, 0.f};

    for (int kbi = 0; kbi < 16; ++kbi) {
        const int buf = kbi & 1;
        if (kbi < 15) stage(buf ^ 1, (kbi + 1) * 64);

#pragma unroll
        for (int kk = 0; kk < 2; ++kk) {
            const int f = hf * 1024 + kbi * 64 + kk * 32;

            // GEMM1 A-frags (W1pad, permuted rows)
            const unsigned short* wbase = w1p + (size_t)f * 32;
            short8 A0 = *(const short8*)(wbase + arow0);
            short8 A1 = *(const short8*)(wbase + arow0 + 128);

            // GEMM2 B-frags from LDS: single per-lane base + nt*2KB imm offsets
            const int cs = (kk * 4 + lg) ^ (li & 7);
            const unsigned short* basep = &Bs[hf][buf][li * 64 + cs * 8];
            short8 bfr[8];
#pragma unroll
            for (int nt = 0; nt < 8; ++nt)
                bfr[nt] = *(const short8*)(basep + nt * 1024);

            // ---- tile 0 ----
            {
                f32x4 p0 = __builtin_amdgcn_mfma_f32_16x16x32_bf16(A0, qf0, zero4, 0, 0, 0);
                f32x4 p1 = __builtin_amdgcn_mfma_f32_16x16x32_bf16(A1, qf0, zero4, 0, 0, 0);
#pragma unroll
                for (int r = 0; r < 4; ++r) {
                    p0[r] = fmaxf(p0[r], 0.f);
                    p1[r] = fmaxf(p1[r], 0.f);
                }
                int4v ai = {(int)cvt_pk(p0[0], p0[1]), (int)cvt_pk(p0[2], p0[3]),
                            (int)cvt_pk(p1[0], p1[1]), (int)cvt_pk(p1[2], p1[3])};
                short8 a2 = __builtin_bit_cast(short8, ai);
#pragma unroll
                for (int nt = 0; nt < 8; ++nt)
                    acc0[nt] = __builtin_amdgcn_mfma_f32_16x16x32_bf16(a2, bfr[nt], acc0[nt], 0, 0, 0);
            }
            // ---- tile 1 ----
            {
                f32x4 p0 = __builtin_amdgcn_mfma_f32_16x16x32_bf16(A0, qf1, zero4, 0, 0, 0);
                f32x4 p1 = __builtin_amdgcn_mfma_f32_16x16x32_bf16(A1, qf1, zero4, 0, 0, 0);
#pragma unroll
                for (int r = 0; r < 4; ++r) {
                    p0[r] = fmaxf(p0[r], 0.f);
                    p1[r] = fmaxf(p1[r], 0.f);
                }
                int4v ai = {(int)cvt_pk(p0[0], p0[1]), (int)cvt_pk(p0[2], p0[3]),
                            (int)cvt_pk(p1[0], p1[1]), (int)cvt_pk(p1[2], p1[3])};
                short8 a2 = __builtin_bit_cast(short8, ai);
#pragma unroll
                for (int nt = 0; nt < 8; ++nt)
                    acc1[nt] = __builtin_amdgcn_mfma_f32_16x16x32_bf16(a2, bfr[nt], acc1[nt], 0, 0, 0);
            }
        }
        __syncthreads();
    }

    // ---- split-K reduction: upper half -> LDS, lower half adds ----
    if (hf == 1) {
#pragma unroll
        for (int mt = 0; mt < 2; ++mt) {
            const f32x4* acc = mt ? acc1 : acc0;
#pragma unroll
            for (int nt = 0; nt < 8; ++nt)
#pragma unroll
                for (int r = 0; r < 4; ++r)
                    red[wvh * 32 + mt * 16 + lg * 4 + r][nt * 16 + li] = acc[nt][r];
        }
    }
    __syncthreads();
    if (hf == 0) {
#pragma unroll
        for (int mt = 0; mt < 2; ++mt) {
            f32x4* acc = mt ? acc1 : acc0;
#pragma unroll
            for (int nt = 0; nt < 8; ++nt)
#pragma unroll
                for (int r = 0; r < 4; ++r)
                    acc[nt][r] += red[wvh * 32 + mt * 16 + lg * 4 + r][nt * 16 + li];
        }

        // ---- epilogue: +b2, +x1 residual, LN2 ----
        float b2v[8], g2v[8], be2v[8];
#pragma unroll
        for (int nt = 0; nt < 8; ++nt) {
            int e = nt * 16 + li;
            b2v[nt] = b2[e]; g2v[nt] = g2[e]; be2v[nt] = be2[e];
        }

        auto epilogue = [&](const f32x4(&acc)[8], int mt) {
#pragma unroll
            for (int r = 0; r < 4; ++r) {
                const int trow = t0 + mt * 16 + lg * 4 + r;
                const float* x1r = x1 + (size_t)trow * 128;
                float vals[8];
                float s1 = 0.f, s2 = 0.f;
#pragma unroll
                for (int nt = 0; nt < 8; ++nt) {
                    float vv = acc[nt][r] + b2v[nt] + x1r[nt * 16 + li];
                    vals[nt] = vv;
                    s1 += vv;
                    s2 += vv * vv;
                }
#pragma unroll
                for (int m = 1; m < 16; m <<= 1) {
                    s1 += __shfl_xor(s1, m);
                    s2 += __shfl_xor(s2, m);
                }
                float mean = s1 * (1.f / 128.f);
                float var = s2 * (1.f / 128.f) - mean * mean;
                float rs = rsqrtf(var + LN_EPS);
                float* orow = out + (size_t)trow * 128;
#pragma unroll
                for (int nt = 0; nt < 8; ++nt)
                    orow[nt * 16 + li] = (vals[nt] - mean) * rs * g2v[nt] + be2v[nt];
            }
        };
        epilogue(acc0, 0);
        epilogue(acc1, 1);
    }
}

extern "C" void kernel_launch(void* const* d_in, const int* in_sizes, int n_in,
                              void* d_out, int out_size, void* d_ws, size_t ws_size,
                              hipStream_t stream) {
    const float* x      = (const float*)d_in[0];
    const float* theta  = (const float*)d_in[1];
    const float* phi    = (const float*)d_in[2];
    const float* w1     = (const float*)d_in[3];
    const float* b1     = (const float*)d_in[4];
    const float* w2     = (const float*)d_in[5];
    const float* b2     = (const float*)d_in[6];
    const float* gamma1 = (const float*)d_in[7];
    const float* beta1  = (const float*)d_in[8];
    const float* gamma2 = (const float*)d_in[9];
    const float* beta2  = (const float*)d_in[10];
    float* out = (float*)d_out;

    char* ws = (char*)d_ws;
    unsigned short* w2b  = (unsigned short*)ws;                  // 512 KB
    unsigned short* w1p  = (unsigned short*)(ws + (512 << 10));  // 128 KB
    unsigned short* qpad = (unsigned short*)(ws + (1 << 20));    // 2 MB

    k_prep<<<264, 256, 0, stream>>>(w2, w1, b1, w2b, w1p);
    k_pre<<<2048, 256, 0, stream>>>(x, theta, phi, gamma1, beta1, out, qpad);
    k_ffn<<<256, 512, 0, stream>>>(out, qpad, w2b, w1p, b2, gamma2, beta2, out);
}